// Round 20
// baseline (1853.426 us; speedup 1.0000x reference)
//
#include <hip/hip_runtime.h>
#include <hip/hip_fp16.h>
#include <math.h>

// Problem constants
#define TT   240
#define BBATCH 64
#define DDIM 7056
#define KENC_PAD 7104          // 7056 padded so each split-K half = 111 BK32 iters
#define NENC 512
#define MHID 256
#define G3   768
#define WRMC 40
#define KWIN 8
#define TOUTC 192
#define RROWS (TOUTC*BBATCH)   // 12288
#define NSTEPS (WRMC + TOUTC)  // 232
#define MN_Z ((size_t)14848*512)   // 7602176

// ws layout (BYTE offsets). Lifetime-disjoint (re-derived r20):
//  [0,7.28M): enc_h (encoder only). Later: gbh fp16 (phase3), gi fp32 [0,45.6M).
//  [8M,69.2M): split-K partials P (encoder only; dead after zreduce).
//  [69.2M,84.4M): z_h (enc out / gi in; dead after gi GEMM, before scan's bts).
//  [37.7M): r1_h (phase3). [45.6M): hopen (phase3). [60.8M): bts (scan out).
//  [73.4M): bts_h. [79.7M): hopen_h. [86M+): persistent smalls.
#define B_GI     ((size_t)0)
#define B_WENCH  ((size_t)0)
#define B_GBH    ((size_t)0)
#define B_P      ((size_t)8388608)
#define B_R1H    ((size_t)37748736)
#define B_HOPEN  ((size_t)45613056)
#define B_BTS    ((size_t)60817408)
#define B_ZH     ((size_t)69206016)
#define B_BTSH   ((size_t)73400320)
#define B_HOPENH ((size_t)79691776)
#define B_WIHH   ((size_t)85983232)
#define B_WHHCH  ((size_t)86769664)
#define B_W1H    ((size_t)87162880)
#define B_W2H    ((size_t)87293952)
#define B_GTAB   ((size_t)87556096)
#define B_WT8    ((size_t)87611392)

typedef _Float16 half8 __attribute__((ext_vector_type(8)));
typedef _Float16 h2v  __attribute__((ext_vector_type(2)));
typedef __attribute__((ext_vector_type(4))) float f32x4;

__device__ __forceinline__ float sigmf(float x) { return 1.0f / (1.0f + expf(-x)); }
__device__ __forceinline__ h2v u2h2(unsigned int u) {
  union { unsigned int u; h2v h; } c; c.u = u; return c.h;
}

// W[N][K] fp32 -> fp16 [N][Kpad] (zero-padded)
__global__ void wconv_kernel(const float* __restrict__ W, __half* __restrict__ o,
                             int N, int K, int Kpad) {
  const int idx = blockIdx.x * 256 + threadIdx.x;
  if (idx >= N * Kpad) return;
  const int n = idx / Kpad, k = idx % Kpad;
  o[idx] = __float2half((k < K) ? W[(size_t)n * K + k] : 0.f);
}

// ---- split-K encoder GEMM: P[bz][M][N] fp32 partials over half-K each ----
// Same tile geometry as gemm_hp (BM=64, BN=256, BK=32, depth-2 prefetch).
__global__ __launch_bounds__(256, 3) void gemm_enc_sk(
    const float* __restrict__ A, const __half* __restrict__ W,
    float* __restrict__ P, int M, int N, int K, int Kpad)
{
  __shared__ __half Ah[2][64][40];
  __shared__ __half Bh[2][256][40];
  const int tid = threadIdx.x;
  const int bx = blockIdx.x, by = blockIdx.y, bz = blockIdx.z;
  const int w = tid >> 6;
  const int lane = tid & 63;
  const int l15 = lane & 15;
  const int khalf = (lane >> 4) * 8;
  const int arow = tid >> 2;
  const int akq = (tid & 3) * 8;
  const int bn = tid >> 2, bk = (tid & 3) * 8;
  const int kbeg = bz * (Kpad / 2);
  const int niter = (Kpad / 2) / 32;

  f32x4 acc[4][4];
#pragma unroll
  for (int i = 0; i < 4; ++i)
#pragma unroll
    for (int j = 0; j < 4; ++j) acc[i][j] = (f32x4){0.f, 0.f, 0.f, 0.f};

  float4 raA0, raA1, rbA0, rbA1, rbA2, rbA3;
  float4 raB0, raB1, rbB0, rbB1, rbB2, rbB3;

#define LOADT(IT, ra0, ra1, rb0, rb1, rb2, rb3)                                   \
  {                                                                               \
    const int k0_ = kbeg + (IT) * 32;                                             \
    ra0 = make_float4(0.f, 0.f, 0.f, 0.f); ra1 = ra0;                             \
    const size_t base_ = (size_t)(by * 64 + arow) * K + k0_ + akq;                \
    if (k0_ + akq < K)     ra0 = *(const float4*)(A + base_);                     \
    if (k0_ + akq + 4 < K) ra1 = *(const float4*)(A + base_ + 4);                 \
    rb0 = *(const float4*)(W + (size_t)(bx * 256 + bn      ) * Kpad + k0_ + bk);  \
    rb1 = *(const float4*)(W + (size_t)(bx * 256 + bn +  64) * Kpad + k0_ + bk);  \
    rb2 = *(const float4*)(W + (size_t)(bx * 256 + bn + 128) * Kpad + k0_ + bk);  \
    rb3 = *(const float4*)(W + (size_t)(bx * 256 + bn + 192) * Kpad + k0_ + bk);  \
  }

#define BODY(IT, ra0, ra1, rb0, rb1, rb2, rb3)                                    \
  {                                                                               \
    __half (*Ac)[40] = Ah[(IT) & 1];                                              \
    __half (*Bc)[40] = Bh[(IT) & 1];                                              \
    __half2 hh_[4];                                                               \
    hh_[0] = __floats2half2_rn(ra0.x, ra0.y);                                     \
    hh_[1] = __floats2half2_rn(ra0.z, ra0.w);                                     \
    hh_[2] = __floats2half2_rn(ra1.x, ra1.y);                                     \
    hh_[3] = __floats2half2_rn(ra1.z, ra1.w);                                     \
    *(float4*)&Ac[arow][akq] = *(float4*)hh_;                                     \
    *(float4*)&Bc[bn      ][bk] = rb0;                                            \
    *(float4*)&Bc[bn +  64][bk] = rb1;                                            \
    *(float4*)&Bc[bn + 128][bk] = rb2;                                            \
    *(float4*)&Bc[bn + 192][bk] = rb3;                                            \
    __syncthreads();                                                              \
    if ((IT) + 2 < niter)                                                         \
      LOADT((IT) + 2, ra0, ra1, rb0, rb1, rb2, rb3);                              \
    half8 ah_[4], bh_[4];                                                         \
    _Pragma("unroll")                                                             \
    for (int i = 0; i < 4; ++i) ah_[i] = *(half8*)&Ac[i * 16 + l15][khalf];       \
    _Pragma("unroll")                                                             \
    for (int j = 0; j < 4; ++j) bh_[j] = *(half8*)&Bc[w * 64 + j * 16 + l15][khalf]; \
    _Pragma("unroll")                                                             \
    for (int i = 0; i < 4; ++i)                                                   \
      _Pragma("unroll")                                                           \
      for (int j = 0; j < 4; ++j)                                                 \
        acc[i][j] = __builtin_amdgcn_mfma_f32_16x16x32_f16(ah_[i], bh_[j], acc[i][j], 0, 0, 0); \
  }

  LOADT(0, raA0, raA1, rbA0, rbA1, rbA2, rbA3);
  LOADT(1, raB0, raB1, rbB0, rbB1, rbB2, rbB3);

  int it = 0;
  while (true) {
    BODY(it, raA0, raA1, rbA0, rbA1, rbA2, rbA3);
    ++it; if (it == niter) break;
    BODY(it, raB0, raB1, rbB0, rbB1, rbB2, rbB3);
    ++it; if (it == niter) break;
  }
#undef BODY
#undef LOADT

  float* Pb = P + (size_t)bz * MN_Z;
  const int r4 = (lane >> 4) * 4;
#pragma unroll
  for (int j = 0; j < 4; ++j) {
    const int col = bx * 256 + w * 64 + j * 16 + l15;
#pragma unroll
    for (int i = 0; i < 4; ++i) {
      const int mbase = by * 64 + i * 16 + r4;
#pragma unroll
      for (int r = 0; r < 4; ++r)
        Pb[(size_t)(mbase + r) * N + col] = acc[i][j][r];
    }
  }
}

// z_h[i] = fp16(P0[i] + P1[i] + bias[i%512]), float4-vectorized
__global__ void zreduce_kernel(const float* __restrict__ P, const float* __restrict__ bias,
                               __half* __restrict__ z) {
  const size_t i4 = ((size_t)blockIdx.x * 256 + threadIdx.x) * 4;
  if (i4 >= MN_Z) return;
  const float4 a = *(const float4*)(P + i4);
  const float4 b = *(const float4*)(P + MN_Z + i4);
  const int col = (int)(i4 & 511);
  __half2 h0 = __floats2half2_rn(a.x + b.x + bias[col],     a.y + b.y + bias[col + 1]);
  __half2 h1 = __floats2half2_rn(a.z + b.z + bias[col + 2], a.w + b.w + bias[col + 3]);
  __half2 hh[2] = {h0, h1};
  *(float2*)(z + i4) = *(float2*)hh;
}

// ---- pipelined fp16 MFMA GEMM (validated r12) ----
template<int AF32>
__global__ __launch_bounds__(256, 3) void gemm_hp(
    const void* __restrict__ A, const __half* __restrict__ W,
    const float* __restrict__ bias, void* __restrict__ C,
    int M, int N, int K, int Kpad, int relu, int out_h, int outk)
{
  __shared__ __half Ah[2][64][40];
  __shared__ __half Bh[2][256][40];
  const int tid = threadIdx.x;
  const int bx = blockIdx.x, by = blockIdx.y;
  const int w = tid >> 6;
  const int lane = tid & 63;
  const int l15 = lane & 15;
  const int khalf = (lane >> 4) * 8;
  const int arow = tid >> 2;
  const int akq = (tid & 3) * 8;
  const int bn = tid >> 2, bk = (tid & 3) * 8;

  f32x4 acc[4][4];
#pragma unroll
  for (int i = 0; i < 4; ++i)
#pragma unroll
    for (int j = 0; j < 4; ++j) acc[i][j] = (f32x4){0.f, 0.f, 0.f, 0.f};

  const int niter = Kpad / 32;

  float4 raA0, raA1, rahA, rbA0, rbA1, rbA2, rbA3;
  float4 raB0, raB1, rahB, rbB0, rbB1, rbB2, rbB3;

#define LOADT(IT, ra0, ra1, rah, rb0, rb1, rb2, rb3)                              \
  {                                                                               \
    const int k0_ = (IT) * 32;                                                    \
    if (AF32) {                                                                   \
      const float* Af_ = (const float*)A;                                         \
      ra0 = make_float4(0.f, 0.f, 0.f, 0.f); ra1 = ra0;                           \
      const size_t base_ = (size_t)(by * 64 + arow) * K + k0_ + akq;              \
      if (k0_ + akq < K)     ra0 = *(const float4*)(Af_ + base_);                 \
      if (k0_ + akq + 4 < K) ra1 = *(const float4*)(Af_ + base_ + 4);             \
    } else {                                                                      \
      rah = *(const float4*)((const __half*)A +                                   \
            (size_t)(by * 64 + arow) * Kpad + k0_ + akq);                         \
    }                                                                             \
    rb0 = *(const float4*)(W + (size_t)(bx * 256 + bn      ) * Kpad + k0_ + bk);  \
    rb1 = *(const float4*)(W + (size_t)(bx * 256 + bn +  64) * Kpad + k0_ + bk);  \
    rb2 = *(const float4*)(W + (size_t)(bx * 256 + bn + 128) * Kpad + k0_ + bk);  \
    rb3 = *(const float4*)(W + (size_t)(bx * 256 + bn + 192) * Kpad + k0_ + bk);  \
  }

#define BODY(IT, ra0, ra1, rah, rb0, rb1, rb2, rb3)                               \
  {                                                                               \
    __half (*Ac)[40] = Ah[(IT) & 1];                                              \
    __half (*Bc)[40] = Bh[(IT) & 1];                                              \
    if (AF32) {                                                                   \
      __half2 hh_[4];                                                             \
      hh_[0] = __floats2half2_rn(ra0.x, ra0.y);                                   \
      hh_[1] = __floats2half2_rn(ra0.z, ra0.w);                                   \
      hh_[2] = __floats2half2_rn(ra1.x, ra1.y);                                   \
      hh_[3] = __floats2half2_rn(ra1.z, ra1.w);                                   \
      *(float4*)&Ac[arow][akq] = *(float4*)hh_;                                   \
    } else {                                                                      \
      *(float4*)&Ac[arow][akq] = rah;                                             \
    }                                                                             \
    *(float4*)&Bc[bn      ][bk] = rb0;                                            \
    *(float4*)&Bc[bn +  64][bk] = rb1;                                            \
    *(float4*)&Bc[bn + 128][bk] = rb2;                                            \
    *(float4*)&Bc[bn + 192][bk] = rb3;                                            \
    __syncthreads();                                                              \
    if ((IT) + 2 < niter)                                                         \
      LOADT((IT) + 2, ra0, ra1, rah, rb0, rb1, rb2, rb3);                         \
    half8 ah_[4], bh_[4];                                                         \
    _Pragma("unroll")                                                             \
    for (int i = 0; i < 4; ++i) ah_[i] = *(half8*)&Ac[i * 16 + l15][khalf];       \
    _Pragma("unroll")                                                             \
    for (int j = 0; j < 4; ++j) bh_[j] = *(half8*)&Bc[w * 64 + j * 16 + l15][khalf]; \
    _Pragma("unroll")                                                             \
    for (int i = 0; i < 4; ++i)                                                   \
      _Pragma("unroll")                                                           \
      for (int j = 0; j < 4; ++j)                                                 \
        acc[i][j] = __builtin_amdgcn_mfma_f32_16x16x32_f16(ah_[i], bh_[j], acc[i][j], 0, 0, 0); \
  }

  LOADT(0, raA0, raA1, rahA, rbA0, rbA1, rbA2, rbA3);
  if (niter > 1) LOADT(1, raB0, raB1, rahB, rbB0, rbB1, rbB2, rbB3);

  int it = 0;
  while (true) {
    BODY(it, raA0, raA1, rahA, rbA0, rbA1, rbA2, rbA3);
    ++it; if (it == niter) break;
    BODY(it, raB0, raB1, rahB, rbB0, rbB1, rbB2, rbB3);
    ++it; if (it == niter) break;
  }
#undef BODY
#undef LOADT

  const int r4 = (lane >> 4) * 4;
#pragma unroll
  for (int j = 0; j < 4; ++j) {
    const int col = bx * 256 + w * 64 + j * 16 + l15;
    const float bc = bias ? bias[col] : 0.f;
#pragma unroll
    for (int i = 0; i < 4; ++i) {
      const int mbase = by * 64 + i * 16 + r4;
#pragma unroll
      for (int r = 0; r < 4; ++r) {
        const int m = mbase + r;
        float vv = acc[i][j][r] + bc;
        if (relu) vv = fmaxf(vv, 0.f);
        if (outk >= 0) {
          const int t = m >> 6, b = m & 63;
          ((float*)C)[(((size_t)(t * KWIN + outk) * BBATCH + b) * NENC) + col] = vv;
        } else if (out_h) {
          ((__half*)C)[(size_t)m * N + col] = __float2half(vv);
        } else {
          ((float*)C)[(size_t)m * N + col] = vv;
        }
      }
    }
  }
}

// gi_table[a][c] = emb[a,:] @ w_ih_c[c,:] + b_ih_c[c]   (18 x 768)
__global__ void gitab_kernel(const float* __restrict__ emb, const float* __restrict__ w_ih_c,
                             const float* __restrict__ b_ih_c, float* __restrict__ gt)
{
  const int idx = blockIdx.x * blockDim.x + threadIdx.x;
  if (idx >= 18 * G3) return;
  const int a = idx / G3, cgate = idx % G3;
  float s = b_ih_c[cgate];
#pragma unroll
  for (int e = 0; e < 32; ++e) s = fmaf(emb[a * 32 + e], w_ih_c[cgate * 32 + e], s);
  gt[idx] = s;
}

// wt8 packing: wt8[k8][j] = float4 holding 8 fp16 = w_hh[j][k8*8 .. k8*8+7].
__global__ void transpose_whh_p8(const float* __restrict__ w, float4* __restrict__ wt8) {
  const int id = blockIdx.x * 256 + threadIdx.x;
  if (id >= 32 * G3) return;
  const int k8 = id / G3, j = id % G3;
  const float* src = w + (size_t)j * MHID + k8 * 8;
  __half2 h2[4];
#pragma unroll
  for (int q = 0; q < 4; ++q)
    h2[q] = __floats2half2_rn(src[2 * q], src[2 * q + 1]);
  wt8[id] = *(float4*)h2;
}

// scan4: register-resident fp16 weights (validated r9-r12, re-locked r17).
__global__ __launch_bounds__(768, 3) void scan4_kernel(
    const float* __restrict__ gi_all, const float4* __restrict__ wt8,
    const float* __restrict__ b_hh, float* __restrict__ bts,
    __half* __restrict__ bts_h)
{
  const int b = blockIdx.x;
  const int j = threadIdx.x;
  __shared__ __align__(16) float hs[256];
  __shared__ __align__(16) __half hs16[256];
  __shared__ float gacc[768];

  unsigned int wreg[128];
#pragma unroll
  for (int k8 = 0; k8 < 32; ++k8) {
    const float4 v = wt8[(size_t)k8 * G3 + j];
    const uint4 u = *(const uint4*)&v;
    wreg[k8 * 4 + 0] = u.x; wreg[k8 * 4 + 1] = u.y;
    wreg[k8 * 4 + 2] = u.z; wreg[k8 * 4 + 3] = u.w;
  }
  const float bj = b_hh[j];
  if (j < 256) { hs[j] = 0.f; hs16[j] = __float2half(0.f); }
  __syncthreads();

  const uint4* h16v = (const uint4*)hs16;

  for (int t = 0; t < NSTEPS; ++t) {
    float gr = 0.f, gz = 0.f, gn = 0.f;
    if (j < 256) {
      const float* gp = gi_all + ((size_t)t * BBATCH + b) * G3;
      gr = gp[j]; gz = gp[256 + j]; gn = gp[512 + j];
    }

    float a0 = bj, a1 = 0.f, a2 = 0.f, a3 = 0.f;
#pragma unroll
    for (int k8 = 0; k8 < 32; ++k8) {
      const uint4 hu = h16v[k8];
#if __has_builtin(__builtin_amdgcn_fdot2)
      a0 = __builtin_amdgcn_fdot2(u2h2(wreg[k8 * 4 + 0]), u2h2(hu.x), a0, false);
      a1 = __builtin_amdgcn_fdot2(u2h2(wreg[k8 * 4 + 1]), u2h2(hu.y), a1, false);
      a2 = __builtin_amdgcn_fdot2(u2h2(wreg[k8 * 4 + 2]), u2h2(hu.z), a2, false);
      a3 = __builtin_amdgcn_fdot2(u2h2(wreg[k8 * 4 + 3]), u2h2(hu.w), a3, false);
#else
      {
        const h2v w0 = u2h2(wreg[k8 * 4 + 0]), w1 = u2h2(wreg[k8 * 4 + 1]);
        const h2v w2 = u2h2(wreg[k8 * 4 + 2]), w3 = u2h2(wreg[k8 * 4 + 3]);
        const h2v x0 = u2h2(hu.x), x1 = u2h2(hu.y), x2 = u2h2(hu.z), x3 = u2h2(hu.w);
        a0 = fmaf((float)w0.x, (float)x0.x, a0); a0 = fmaf((float)w0.y, (float)x0.y, a0);
        a1 = fmaf((float)w1.x, (float)x1.x, a1); a1 = fmaf((float)w1.y, (float)x1.y, a1);
        a2 = fmaf((float)w2.x, (float)x2.x, a2); a2 = fmaf((float)w2.y, (float)x2.y, a2);
        a3 = fmaf((float)w3.x, (float)x3.x, a3); a3 = fmaf((float)w3.y, (float)x3.y, a3);
      }
#endif
    }
    gacc[j] = (a0 + a1) + (a2 + a3);
    __syncthreads();

    if (j < 256) {
      const float r = sigmf(gr + gacc[j]);
      const float z = sigmf(gz + gacc[256 + j]);
      const float n = tanhf(gn + r * gacc[512 + j]);   // b_hh_n inside r* via acc init
      const float hn = (1.f - z) * n + z * hs[j];
      hs[j] = hn;
      hs16[j] = __float2half(hn);
      if (t >= WRMC) {
        const size_t o = (((size_t)(t - WRMC)) * BBATCH + b) * MHID + j;
        bts[o] = hn;
        bts_h[o] = __float2half(hn);
      }
    }
    __syncthreads();
  }
}

// Open-loop gate combine; gh fp16 (r19-validated)
__global__ __launch_bounds__(256) void open_gates(
    const float* __restrict__ gtab, const int* __restrict__ act_seq,
    const __half* __restrict__ gh, const float* __restrict__ hin,
    float* __restrict__ hout, __half* __restrict__ hout_h, int kstep)
{
  const int row = blockIdx.x;
  const int j = threadIdx.x;
  const int t = row >> 6, b = row & 63;
  const int a = act_seq[(WRMC + t + kstep) * BBATCH + b];
  const float* gi = gtab + a * G3;
  const float gr = gi[j], gz = gi[256 + j], gn = gi[512 + j];
  const size_t g0 = (size_t)row * G3;
  const float hr = __half2float(gh[g0 + j]);
  const float hz = __half2float(gh[g0 + 256 + j]);
  const float hnn = __half2float(gh[g0 + 512 + j]);
  const float h = hin[(size_t)row * MHID + j];
  const float r = sigmf(gr + hr);
  const float z = sigmf(gz + hz);
  const float n = tanhf(gn + r * hnn);
  const float hn = (1.f - z) * n + z * h;
  hout[(size_t)row * MHID + j] = hn;
  hout_h[(size_t)row * MHID + j] = __float2half(hn);
}

extern "C" void kernel_launch(void* const* d_in, const int* in_sizes, int n_in,
                              void* d_out, int out_size, void* d_ws, size_t ws_size,
                              hipStream_t stream) {
  const float* obs    = (const float*)d_in[0];
  const int*   act    = (const int*)  d_in[1];
  const float* w_enc  = (const float*)d_in[2];
  const float* b_enc  = (const float*)d_in[3];
  const float* w_ih   = (const float*)d_in[4];
  const float* w_hh   = (const float*)d_in[5];
  const float* b_ih   = (const float*)d_in[6];
  const float* b_hh   = (const float*)d_in[7];
  const float* w_ih_c = (const float*)d_in[8];
  const float* w_hh_c = (const float*)d_in[9];
  const float* b_ih_c = (const float*)d_in[10];
  const float* b_hh_c = (const float*)d_in[11];
  const float* W1     = (const float*)d_in[12];
  const float* b1     = (const float*)d_in[13];
  const float* W2     = (const float*)d_in[14];
  const float* b2     = (const float*)d_in[15];
  const float* emb    = (const float*)d_in[16];

  char* wsb = (char*)d_ws;
  float* out = (float*)d_out;

  float*  gi      = (float*)(wsb + B_GI);
  __half* gbh     = (__half*)(wsb + B_GBH);
  float*  P       = (float*)(wsb + B_P);
  __half* r1_h    = (__half*)(wsb + B_R1H);
  __half* z_h     = (__half*)(wsb + B_ZH);
  float*  hopen   = (float*)(wsb + B_HOPEN);
  float*  bts     = (float*)(wsb + B_BTS);
  __half* bts_h   = (__half*)(wsb + B_BTSH);
  __half* hopen_h = (__half*)(wsb + B_HOPENH);
  __half* enc_h   = (__half*)(wsb + B_WENCH);
  __half* ih_h    = (__half*)(wsb + B_WIHH);
  __half* hhc_h   = (__half*)(wsb + B_WHHCH);
  __half* w1_h    = (__half*)(wsb + B_W1H);
  __half* w2_h    = (__half*)(wsb + B_W2H);
  float*  gtab    = (float*)(wsb + B_GTAB);
  float4* wt8     = (float4*)(wsb + B_WT8);

  const dim3 blk(256);

  // Weight fp16 conversions + small tables
  wconv_kernel<<<(NENC * KENC_PAD + 255) / 256, blk, 0, stream>>>(w_enc, enc_h, NENC, DDIM, KENC_PAD);
  wconv_kernel<<<(G3 * NENC + 255) / 256, blk, 0, stream>>>(w_ih, ih_h, G3, NENC, NENC);
  wconv_kernel<<<(G3 * MHID + 255) / 256, blk, 0, stream>>>(w_hh_c, hhc_h, G3, MHID, MHID);
  wconv_kernel<<<(MHID * MHID + 255) / 256, blk, 0, stream>>>(W1, w1_h, MHID, MHID, MHID);
  wconv_kernel<<<(NENC * MHID + 255) / 256, blk, 0, stream>>>(W2, w2_h, NENC, MHID, MHID);
  gitab_kernel<<<54, 256, 0, stream>>>(emb, w_ih_c, b_ih_c, gtab);
  transpose_whh_p8<<<(32 * G3 + 255) / 256, blk, 0, stream>>>(w_hh, wt8);

  // Phase 1a: encoder split-K=2 (928 blocks) + reduce to fp16 z
  gemm_enc_sk<<<dim3(NENC / 256, NSTEPS * BBATCH / 64, 2), blk, 0, stream>>>(
      obs, enc_h, P, NSTEPS * BBATCH, NENC, DDIM, KENC_PAD);
  zreduce_kernel<<<(int)((MN_Z / 4 + 255) / 256), blk, 0, stream>>>(P, b_enc, z_h);

  // Phase 1b: input gates
  gemm_hp<0><<<dim3(G3 / 256, NSTEPS * BBATCH / 64), blk, 0, stream>>>(
      z_h, ih_h, b_ih, gi, NSTEPS * BBATCH, G3, NENC, NENC, 0, 0, -1);

  // Phase 2: sequential GRU scan (register-resident fp16 weights)
  scan4_kernel<<<BBATCH, 768, 0, stream>>>(gi, wt8, b_hh, bts, bts_h);

  // Phase 3: open-loop rollout (r12-validated pipeline; gbh fp16)
  for (int k = 0; k < KWIN; ++k) {
    const __half* hin_h = (k == 0) ? bts_h : hopen_h;
    const float*  hin   = (k == 0) ? bts   : hopen;
    gemm_hp<0><<<dim3(G3 / 256, RROWS / 64), blk, 0, stream>>>(
        hin_h, hhc_h, b_hh_c, gbh, RROWS, G3, MHID, MHID, 0, 1, -1);
    open_gates<<<RROWS, 256, 0, stream>>>(gtab, act, gbh, hin, hopen, hopen_h, k);
    gemm_hp<0><<<dim3(MHID / 256, RROWS / 64), blk, 0, stream>>>(
        hopen_h, w1_h, b1, r1_h, RROWS, MHID, MHID, MHID, 1, 1, -1);
    gemm_hp<0><<<dim3(NENC / 256, RROWS / 64), blk, 0, stream>>>(
        r1_h, w2_h, b2, out, RROWS, NENC, MHID, MHID, 0, 0, k);
  }
}

// Round 21
// 1089.626 us; speedup vs baseline: 1.7010x; 1.7010x over previous
//
#include <hip/hip_runtime.h>
#include <hip/hip_fp16.h>
#include <math.h>

// Problem constants
#define TT   240
#define BBATCH 64
#define DDIM 7056
#define KENC_PAD 7072          // 7056 padded to %32
#define NENC 512
#define MHID 256
#define G3   768
#define WRMC 40
#define KWIN 8
#define TOUTC 192
#define RROWS (TOUTC*BBATCH)   // 12288
#define NSTEPS (WRMC + TOUTC)  // 232

// ws layout (BYTE offsets). Lifetime-disjoint; peak 88.0 MB <= 91.8 validated.
#define B_GI     ((size_t)0)
#define B_WENCH  ((size_t)0)
#define B_GBH    ((size_t)0)                 // fp16: 12288*768*2 = 18.9MB
#define B_R1H    ((size_t)37748736)
#define B_ZH     ((size_t)45613056)
#define B_HOPEN  ((size_t)45613056)
#define B_BTS    ((size_t)60817408)
#define B_BTSH   ((size_t)73400320)
#define B_HOPENH ((size_t)79691776)
#define B_WIHH   ((size_t)85983232)
#define B_WHHCH  ((size_t)86769664)
#define B_W1H    ((size_t)87162880)
#define B_W2H    ((size_t)87293952)
#define B_GTAB   ((size_t)87556096)
#define B_WT8    ((size_t)87611392)

typedef _Float16 half8 __attribute__((ext_vector_type(8)));
typedef _Float16 h2v  __attribute__((ext_vector_type(2)));
typedef __attribute__((ext_vector_type(4))) float f32x4;

__device__ __forceinline__ float sigmf(float x) { return 1.0f / (1.0f + expf(-x)); }
__device__ __forceinline__ h2v u2h2(unsigned int u) {
  union { unsigned int u; h2v h; } c; c.u = u; return c.h;
}

// W[N][K] fp32 -> fp16 [N][Kpad] (zero-padded)
__global__ void wconv_kernel(const float* __restrict__ W, __half* __restrict__ o,
                             int N, int K, int Kpad) {
  const int idx = blockIdx.x * 256 + threadIdx.x;
  if (idx >= N * Kpad) return;
  const int n = idx / Kpad, k = idx % Kpad;
  o[idx] = __float2half((k < K) ? W[(size_t)n * K + k] : 0.f);
}

// ---- pipelined fp16 MFMA GEMM (validated r12) ----
// BM=64, BN=256, BK=32, 4 waves; depth-2 register prefetch, 1 barrier/iter.
template<int AF32>
__global__ __launch_bounds__(256, 3) void gemm_hp(
    const void* __restrict__ A, const __half* __restrict__ W,
    const float* __restrict__ bias, void* __restrict__ C,
    int M, int N, int K, int Kpad, int relu, int out_h, int outk)
{
  __shared__ __half Ah[2][64][40];
  __shared__ __half Bh[2][256][40];
  const int tid = threadIdx.x;
  const int bx = blockIdx.x, by = blockIdx.y;
  const int w = tid >> 6;
  const int lane = tid & 63;
  const int l15 = lane & 15;
  const int khalf = (lane >> 4) * 8;
  const int arow = tid >> 2;
  const int akq = (tid & 3) * 8;
  const int bn = tid >> 2, bk = (tid & 3) * 8;

  f32x4 acc[4][4];
#pragma unroll
  for (int i = 0; i < 4; ++i)
#pragma unroll
    for (int j = 0; j < 4; ++j) acc[i][j] = (f32x4){0.f, 0.f, 0.f, 0.f};

  const int niter = Kpad / 32;

  float4 raA0, raA1, rahA, rbA0, rbA1, rbA2, rbA3;
  float4 raB0, raB1, rahB, rbB0, rbB1, rbB2, rbB3;

#define LOADT(IT, ra0, ra1, rah, rb0, rb1, rb2, rb3)                              \
  {                                                                               \
    const int k0_ = (IT) * 32;                                                    \
    if (AF32) {                                                                   \
      const float* Af_ = (const float*)A;                                         \
      ra0 = make_float4(0.f, 0.f, 0.f, 0.f); ra1 = ra0;                           \
      const size_t base_ = (size_t)(by * 64 + arow) * K + k0_ + akq;              \
      if (k0_ + akq < K)     ra0 = *(const float4*)(Af_ + base_);                 \
      if (k0_ + akq + 4 < K) ra1 = *(const float4*)(Af_ + base_ + 4);             \
    } else {                                                                      \
      rah = *(const float4*)((const __half*)A +                                   \
            (size_t)(by * 64 + arow) * Kpad + k0_ + akq);                         \
    }                                                                             \
    rb0 = *(const float4*)(W + (size_t)(bx * 256 + bn      ) * Kpad + k0_ + bk);  \
    rb1 = *(const float4*)(W + (size_t)(bx * 256 + bn +  64) * Kpad + k0_ + bk);  \
    rb2 = *(const float4*)(W + (size_t)(bx * 256 + bn + 128) * Kpad + k0_ + bk);  \
    rb3 = *(const float4*)(W + (size_t)(bx * 256 + bn + 192) * Kpad + k0_ + bk);  \
  }

#define BODY(IT, ra0, ra1, rah, rb0, rb1, rb2, rb3)                               \
  {                                                                               \
    __half (*Ac)[40] = Ah[(IT) & 1];                                              \
    __half (*Bc)[40] = Bh[(IT) & 1];                                              \
    if (AF32) {                                                                   \
      __half2 hh_[4];                                                             \
      hh_[0] = __floats2half2_rn(ra0.x, ra0.y);                                   \
      hh_[1] = __floats2half2_rn(ra0.z, ra0.w);                                   \
      hh_[2] = __floats2half2_rn(ra1.x, ra1.y);                                   \
      hh_[3] = __floats2half2_rn(ra1.z, ra1.w);                                   \
      *(float4*)&Ac[arow][akq] = *(float4*)hh_;                                   \
    } else {                                                                      \
      *(float4*)&Ac[arow][akq] = rah;                                             \
    }                                                                             \
    *(float4*)&Bc[bn      ][bk] = rb0;                                            \
    *(float4*)&Bc[bn +  64][bk] = rb1;                                            \
    *(float4*)&Bc[bn + 128][bk] = rb2;                                            \
    *(float4*)&Bc[bn + 192][bk] = rb3;                                            \
    __syncthreads();                                                              \
    if ((IT) + 2 < niter)                                                         \
      LOADT((IT) + 2, ra0, ra1, rah, rb0, rb1, rb2, rb3);                         \
    half8 ah_[4], bh_[4];                                                         \
    _Pragma("unroll")                                                             \
    for (int i = 0; i < 4; ++i) ah_[i] = *(half8*)&Ac[i * 16 + l15][khalf];       \
    _Pragma("unroll")                                                             \
    for (int j = 0; j < 4; ++j) bh_[j] = *(half8*)&Bc[w * 64 + j * 16 + l15][khalf]; \
    _Pragma("unroll")                                                             \
    for (int i = 0; i < 4; ++i)                                                   \
      _Pragma("unroll")                                                           \
      for (int j = 0; j < 4; ++j)                                                 \
        acc[i][j] = __builtin_amdgcn_mfma_f32_16x16x32_f16(ah_[i], bh_[j], acc[i][j], 0, 0, 0); \
  }

  LOADT(0, raA0, raA1, rahA, rbA0, rbA1, rbA2, rbA3);
  if (niter > 1) LOADT(1, raB0, raB1, rahB, rbB0, rbB1, rbB2, rbB3);

  int it = 0;
  while (true) {
    BODY(it, raA0, raA1, rahA, rbA0, rbA1, rbA2, rbA3);
    ++it; if (it == niter) break;
    BODY(it, raB0, raB1, rahB, rbB0, rbB1, rbB2, rbB3);
    ++it; if (it == niter) break;
  }
#undef BODY
#undef LOADT

  // epilogue: row = by*64 + i*16 + (lane>>4)*4 + r ; col = bx*256 + w*64 + j*16 + l15
  const int r4 = (lane >> 4) * 4;
#pragma unroll
  for (int j = 0; j < 4; ++j) {
    const int col = bx * 256 + w * 64 + j * 16 + l15;
    const float bc = bias ? bias[col] : 0.f;
#pragma unroll
    for (int i = 0; i < 4; ++i) {
      const int mbase = by * 64 + i * 16 + r4;
#pragma unroll
      for (int r = 0; r < 4; ++r) {
        const int m = mbase + r;
        float vv = acc[i][j][r] + bc;
        if (relu) vv = fmaxf(vv, 0.f);
        if (outk >= 0) {
          const int t = m >> 6, b = m & 63;
          ((float*)C)[(((size_t)(t * KWIN + outk) * BBATCH + b) * NENC) + col] = vv;
        } else if (out_h) {
          ((__half*)C)[(size_t)m * N + col] = __float2half(vv);
        } else {
          ((float*)C)[(size_t)m * N + col] = vv;
        }
      }
    }
  }
}

// gi_table[a][c] = emb[a,:] @ w_ih_c[c,:] + b_ih_c[c]   (18 x 768)
__global__ void gitab_kernel(const float* __restrict__ emb, const float* __restrict__ w_ih_c,
                             const float* __restrict__ b_ih_c, float* __restrict__ gt)
{
  const int idx = blockIdx.x * blockDim.x + threadIdx.x;
  if (idx >= 18 * G3) return;
  const int a = idx / G3, cgate = idx % G3;
  float s = b_ih_c[cgate];
#pragma unroll
  for (int e = 0; e < 32; ++e) s = fmaf(emb[a * 32 + e], w_ih_c[cgate * 32 + e], s);
  gt[idx] = s;
}

// wt8 packing: wt8[k8][j] = float4 holding 8 fp16 = w_hh[j][k8*8 .. k8*8+7].
__global__ void transpose_whh_p8(const float* __restrict__ w, float4* __restrict__ wt8) {
  const int id = blockIdx.x * 256 + threadIdx.x;
  if (id >= 32 * G3) return;
  const int k8 = id / G3, j = id % G3;
  const float* src = w + (size_t)j * MHID + k8 * 8;
  __half2 h2[4];
#pragma unroll
  for (int q = 0; q < 4; ++q)
    h2[q] = __floats2half2_rn(src[2 * q], src[2 * q + 1]);
  wt8[id] = *(float4*)h2;
}

// scan4: register-resident fp16 weights (validated r9-r12, re-locked r17/r19).
__global__ __launch_bounds__(768, 3) void scan4_kernel(
    const float* __restrict__ gi_all, const float4* __restrict__ wt8,
    const float* __restrict__ b_hh, float* __restrict__ bts,
    __half* __restrict__ bts_h)
{
  const int b = blockIdx.x;
  const int j = threadIdx.x;
  __shared__ __align__(16) float hs[256];
  __shared__ __align__(16) __half hs16[256];
  __shared__ float gacc[768];

  unsigned int wreg[128];
#pragma unroll
  for (int k8 = 0; k8 < 32; ++k8) {
    const float4 v = wt8[(size_t)k8 * G3 + j];
    const uint4 u = *(const uint4*)&v;
    wreg[k8 * 4 + 0] = u.x; wreg[k8 * 4 + 1] = u.y;
    wreg[k8 * 4 + 2] = u.z; wreg[k8 * 4 + 3] = u.w;
  }
  const float bj = b_hh[j];
  if (j < 256) { hs[j] = 0.f; hs16[j] = __float2half(0.f); }
  __syncthreads();

  const uint4* h16v = (const uint4*)hs16;

  for (int t = 0; t < NSTEPS; ++t) {
    float gr = 0.f, gz = 0.f, gn = 0.f;
    if (j < 256) {
      const float* gp = gi_all + ((size_t)t * BBATCH + b) * G3;
      gr = gp[j]; gz = gp[256 + j]; gn = gp[512 + j];
    }

    float a0 = bj, a1 = 0.f, a2 = 0.f, a3 = 0.f;
#pragma unroll
    for (int k8 = 0; k8 < 32; ++k8) {
      const uint4 hu = h16v[k8];
#if __has_builtin(__builtin_amdgcn_fdot2)
      a0 = __builtin_amdgcn_fdot2(u2h2(wreg[k8 * 4 + 0]), u2h2(hu.x), a0, false);
      a1 = __builtin_amdgcn_fdot2(u2h2(wreg[k8 * 4 + 1]), u2h2(hu.y), a1, false);
      a2 = __builtin_amdgcn_fdot2(u2h2(wreg[k8 * 4 + 2]), u2h2(hu.z), a2, false);
      a3 = __builtin_amdgcn_fdot2(u2h2(wreg[k8 * 4 + 3]), u2h2(hu.w), a3, false);
#else
      {
        const h2v w0 = u2h2(wreg[k8 * 4 + 0]), w1 = u2h2(wreg[k8 * 4 + 1]);
        const h2v w2 = u2h2(wreg[k8 * 4 + 2]), w3 = u2h2(wreg[k8 * 4 + 3]);
        const h2v x0 = u2h2(hu.x), x1 = u2h2(hu.y), x2 = u2h2(hu.z), x3 = u2h2(hu.w);
        a0 = fmaf((float)w0.x, (float)x0.x, a0); a0 = fmaf((float)w0.y, (float)x0.y, a0);
        a1 = fmaf((float)w1.x, (float)x1.x, a1); a1 = fmaf((float)w1.y, (float)x1.y, a1);
        a2 = fmaf((float)w2.x, (float)x2.x, a2); a2 = fmaf((float)w2.y, (float)x2.y, a2);
        a3 = fmaf((float)w3.x, (float)x3.x, a3); a3 = fmaf((float)w3.y, (float)x3.y, a3);
      }
#endif
    }
    gacc[j] = (a0 + a1) + (a2 + a3);
    __syncthreads();

    if (j < 256) {
      const float r = sigmf(gr + gacc[j]);
      const float z = sigmf(gz + gacc[256 + j]);
      const float n = tanhf(gn + r * gacc[512 + j]);   // b_hh_n inside r* via acc init
      const float hn = (1.f - z) * n + z * hs[j];
      hs[j] = hn;
      hs16[j] = __float2half(hn);
      if (t >= WRMC) {
        const size_t o = (((size_t)(t - WRMC)) * BBATCH + b) * MHID + j;
        bts[o] = hn;
        bts_h[o] = __float2half(hn);
      }
    }
    __syncthreads();
  }
}

// Open-loop gate combine; gh fp16 (r19-validated)
__global__ __launch_bounds__(256) void open_gates(
    const float* __restrict__ gtab, const int* __restrict__ act_seq,
    const __half* __restrict__ gh, const float* __restrict__ hin,
    float* __restrict__ hout, __half* __restrict__ hout_h, int kstep)
{
  const int row = blockIdx.x;
  const int j = threadIdx.x;
  const int t = row >> 6, b = row & 63;
  const int a = act_seq[(WRMC + t + kstep) * BBATCH + b];
  const float* gi = gtab + a * G3;
  const float gr = gi[j], gz = gi[256 + j], gn = gi[512 + j];
  const size_t g0 = (size_t)row * G3;
  const float hr = __half2float(gh[g0 + j]);
  const float hz = __half2float(gh[g0 + 256 + j]);
  const float hnn = __half2float(gh[g0 + 512 + j]);
  const float h = hin[(size_t)row * MHID + j];
  const float r = sigmf(gr + hr);
  const float z = sigmf(gz + hz);
  const float n = tanhf(gn + r * hnn);
  const float hn = (1.f - z) * n + z * h;
  hout[(size_t)row * MHID + j] = hn;
  hout_h[(size_t)row * MHID + j] = __float2half(hn);
}

extern "C" void kernel_launch(void* const* d_in, const int* in_sizes, int n_in,
                              void* d_out, int out_size, void* d_ws, size_t ws_size,
                              hipStream_t stream) {
  const float* obs    = (const float*)d_in[0];
  const int*   act    = (const int*)  d_in[1];
  const float* w_enc  = (const float*)d_in[2];
  const float* b_enc  = (const float*)d_in[3];
  const float* w_ih   = (const float*)d_in[4];
  const float* w_hh   = (const float*)d_in[5];
  const float* b_ih   = (const float*)d_in[6];
  const float* b_hh   = (const float*)d_in[7];
  const float* w_ih_c = (const float*)d_in[8];
  const float* w_hh_c = (const float*)d_in[9];
  const float* b_ih_c = (const float*)d_in[10];
  const float* b_hh_c = (const float*)d_in[11];
  const float* W1     = (const float*)d_in[12];
  const float* b1     = (const float*)d_in[13];
  const float* W2     = (const float*)d_in[14];
  const float* b2     = (const float*)d_in[15];
  const float* emb    = (const float*)d_in[16];

  char* wsb = (char*)d_ws;
  float* out = (float*)d_out;

  float*  gi      = (float*)(wsb + B_GI);
  __half* gbh     = (__half*)(wsb + B_GBH);
  __half* r1_h    = (__half*)(wsb + B_R1H);
  __half* z_h     = (__half*)(wsb + B_ZH);
  float*  hopen   = (float*)(wsb + B_HOPEN);
  float*  bts     = (float*)(wsb + B_BTS);
  __half* bts_h   = (__half*)(wsb + B_BTSH);
  __half* hopen_h = (__half*)(wsb + B_HOPENH);
  __half* enc_h   = (__half*)(wsb + B_WENCH);
  __half* ih_h    = (__half*)(wsb + B_WIHH);
  __half* hhc_h   = (__half*)(wsb + B_WHHCH);
  __half* w1_h    = (__half*)(wsb + B_W1H);
  __half* w2_h    = (__half*)(wsb + B_W2H);
  float*  gtab    = (float*)(wsb + B_GTAB);
  float4* wt8     = (float4*)(wsb + B_WT8);

  const dim3 blk(256);

  // Weight fp16 conversions + small tables
  wconv_kernel<<<(NENC * KENC_PAD + 255) / 256, blk, 0, stream>>>(w_enc, enc_h, NENC, DDIM, KENC_PAD);
  wconv_kernel<<<(G3 * NENC + 255) / 256, blk, 0, stream>>>(w_ih, ih_h, G3, NENC, NENC);
  wconv_kernel<<<(G3 * MHID + 255) / 256, blk, 0, stream>>>(w_hh_c, hhc_h, G3, MHID, MHID);
  wconv_kernel<<<(MHID * MHID + 255) / 256, blk, 0, stream>>>(W1, w1_h, MHID, MHID, MHID);
  wconv_kernel<<<(NENC * MHID + 255) / 256, blk, 0, stream>>>(W2, w2_h, NENC, MHID, MHID);
  gitab_kernel<<<54, 256, 0, stream>>>(emb, w_ih_c, b_ih_c, gtab);
  transpose_whh_p8<<<(32 * G3 + 255) / 256, blk, 0, stream>>>(w_hh, wt8);

  // Phase 1: encoder (fp32 A, in-staging cvt; fp16 z out) + input gates
  gemm_hp<1><<<dim3(NENC / 256, NSTEPS * BBATCH / 64), blk, 0, stream>>>(
      obs, enc_h, b_enc, z_h, NSTEPS * BBATCH, NENC, DDIM, KENC_PAD, 0, 1, -1);
  gemm_hp<0><<<dim3(G3 / 256, NSTEPS * BBATCH / 64), blk, 0, stream>>>(
      z_h, ih_h, b_ih, gi, NSTEPS * BBATCH, G3, NENC, NENC, 0, 0, -1);

  // Phase 2: sequential GRU scan (register-resident fp16 weights)
  scan4_kernel<<<BBATCH, 768, 0, stream>>>(gi, wt8, b_hh, bts, bts_h);

  // Phase 3: open-loop rollout (r12-validated pipeline; gbh fp16)
  for (int k = 0; k < KWIN; ++k) {
    const __half* hin_h = (k == 0) ? bts_h : hopen_h;
    const float*  hin   = (k == 0) ? bts   : hopen;
    gemm_hp<0><<<dim3(G3 / 256, RROWS / 64), blk, 0, stream>>>(
        hin_h, hhc_h, b_hh_c, gbh, RROWS, G3, MHID, MHID, 0, 1, -1);
    open_gates<<<RROWS, 256, 0, stream>>>(gtab, act, gbh, hin, hopen, hopen_h, k);
    gemm_hp<0><<<dim3(MHID / 256, RROWS / 64), blk, 0, stream>>>(
        hopen_h, w1_h, b1, r1_h, RROWS, MHID, MHID, MHID, 1, 1, -1);
    gemm_hp<0><<<dim3(NENC / 256, RROWS / 64), blk, 0, stream>>>(
        r1_h, w2_h, b2, out, RROWS, NENC, MHID, MHID, 0, 0, k);
  }
}